// Round 13
// baseline (243.329 us; speedup 1.0000x reference)
//
#include <hip/hip_runtime.h>

#define NROWS 1000000
#define NB    3907         // ceil(1e6 / 256) mask blocks
#define NT    62500        // 16-row tiles
#define TPB   4            // tiles per wave-batch
#define NBATCH (NT / TPB)  // 15625, exact
#define MLP_BLOCKS 768
#define MLP_THREADS 512

typedef __bf16 bf16x8 __attribute__((ext_vector_type(8)));
typedef float  f32x4  __attribute__((ext_vector_type(4)));

__device__ __forceinline__ unsigned cvt_pk_bf16(float lo, float hi) {
  unsigned r;
  asm("v_cvt_pk_bf16_f32 %0, %1, %2" : "=v"(r) : "v"(lo), "v"(hi));
  return r;
}

// ---------------------------------------------------------------------------
// Kernel 1: per-256-row-block nonzero counts (3907 sums).
// ---------------------------------------------------------------------------
__global__ __launch_bounds__(256) void count_kernel(
    const int* __restrict__ mask, int* __restrict__ bsum) {
  int tid = threadIdx.x;
  int row = blockIdx.x * 256 + tid;
  int cnt = 0;
  if (row < NROWS) {
    const int4* mp = (const int4*)(mask + (long)row * 8);
    int4 a = mp[0], b = mp[1];
    cnt = (a.x != 0) + (a.y != 0) + (a.z != 0) + (a.w != 0) +
          (b.x != 0) + (b.y != 0) + (b.z != 0) + (b.w != 0);
  }
#pragma unroll
  for (int off = 1; off < 64; off <<= 1) cnt += __shfl_xor(cnt, off);
  __shared__ int ws[4];
  if ((tid & 63) == 0) ws[tid >> 6] = cnt;
  __syncthreads();
  if (tid == 0) bsum[blockIdx.x] = ws[0] + ws[1] + ws[2] + ws[3];
}

// ---------------------------------------------------------------------------
// Kernel 2: exclusive scan of 3907 block sums (single block).
// ---------------------------------------------------------------------------
__global__ __launch_bounds__(1024) void scan_kernel(
    const int* __restrict__ bsum, int* __restrict__ boff) {
  __shared__ int lds[1024];
  int t = threadIdx.x;
  int i0 = t * 4;
  int c0 = (i0 + 0 < NB) ? bsum[i0 + 0] : 0;
  int c1 = (i0 + 1 < NB) ? bsum[i0 + 1] : 0;
  int c2 = (i0 + 2 < NB) ? bsum[i0 + 2] : 0;
  int c3 = (i0 + 3 < NB) ? bsum[i0 + 3] : 0;
  int s = c0 + c1 + c2 + c3;
  lds[t] = s;
  __syncthreads();
  for (int off = 1; off < 1024; off <<= 1) {
    int v = lds[t];
    int add = (t >= off) ? lds[t - off] : 0;
    __syncthreads();
    lds[t] = v + add;
    __syncthreads();
  }
  int excl = lds[t] - s;
  if (i0 + 0 < NB) boff[i0 + 0] = excl;
  excl += c0;
  if (i0 + 1 < NB) boff[i0 + 1] = excl;
  excl += c1;
  if (i0 + 2 < NB) boff[i0 + 2] = excl;
  excl += c2;
  if (i0 + 3 < NB) boff[i0 + 3] = excl;
}

// ---------------------------------------------------------------------------
// Kernel 3: per-row info = (scatter_pos << 8) | mask_bits.
// ---------------------------------------------------------------------------
__global__ __launch_bounds__(256) void expand_kernel(
    const int* __restrict__ mask, const int* __restrict__ boff,
    int* __restrict__ rowinfo) {
  int tid = threadIdx.x;
  int row = blockIdx.x * 256 + tid;
  bool valid = row < NROWS;
  unsigned mb = 0;
  int cnt = 0;
  if (valid) {
    const int4* mp = (const int4*)(mask + (long)row * 8);
    int4 a = mp[0], b = mp[1];
    mb = (unsigned)((a.x != 0) | ((a.y != 0) << 1) | ((a.z != 0) << 2) |
                    ((a.w != 0) << 3) | ((b.x != 0) << 4) | ((b.y != 0) << 5) |
                    ((b.z != 0) << 6) | ((b.w != 0) << 7));
    cnt = __popc(mb);
  }
  int incl = cnt;
#pragma unroll
  for (int off = 1; off < 64; off <<= 1) {
    int v = __shfl_up(incl, off);
    if ((tid & 63) >= off) incl += v;
  }
  __shared__ int wsum[4];
  if ((tid & 63) == 63) wsum[tid >> 6] = incl;
  __syncthreads();
  int w = tid >> 6;
  int wo = 0;
  if (w > 0) wo += wsum[0];
  if (w > 1) wo += wsum[1];
  if (w > 2) wo += wsum[2];
  int pos = boff[blockIdx.x] + wo + (incl - cnt);
  if (valid) rowinfo[row] = (pos << 8) | (int)mb;
}

// ---------------------------------------------------------------------------
// Kernel 4 (ABLATION TEMPLATE): MODE 0=full(real out), 1=noepi, 2=nocvt,
// 3=nox. Variants 1-3 keep compute live via keep-sum -> dbg store.
// ---------------------------------------------------------------------------
template <int MODE>
__global__ __launch_bounds__(MLP_THREADS, 4) void mlp_t(
    const float* __restrict__ x, const float* __restrict__ w0,
    const float* __restrict__ b0, const float* __restrict__ w1,
    const float* __restrict__ b1, const int* __restrict__ rowinfo,
    float* __restrict__ out, float* __restrict__ dbg) {
  __shared__ __bf16 sA[32 * 64 * 8];
  __shared__ float sB0[512];

  int tid = threadIdx.x;
#pragma unroll
  for (int i = 0; i < 4; ++i) {
    int fi = i * MLP_THREADS + tid;
    int frag = fi >> 6;
    int lane = fi & 63;
    int d = frag >> 2, qb = frag & 3;
    int q = qb * 16 + (lane & 15);
    int kb = (lane >> 4) * 8;
    bf16x8 v;
#pragma unroll
    for (int j = 0; j < 8; ++j)
      v[j] = (__bf16)w0[d * 2048 + (kb + j) * 64 + q];
    *(bf16x8*)&sA[fi * 8] = v;
  }
  if (tid < 128) *(float4*)&sB0[tid * 4] = *(const float4*)&b0[tid * 4];
  __syncthreads();

  int l = tid & 63;
  int n = l & 15;
  int g = l >> 4;

  bf16x8 w1A, w1B;
  bool ownrow = (n < 8);
#pragma unroll
  for (int j = 0; j < 8; ++j) {
    int off = (j >> 2) * 16 + g * 4 + (j & 3);
    w1A[j] = ownrow ? (__bf16)w1[n * 64 + off]      : (__bf16)0.f;
    w1B[j] = ownrow ? (__bf16)w1[n * 64 + 32 + off] : (__bf16)0.f;
  }
  int4 w1Ai = *(int4*)&w1A;
  int4 w1Bi = *(int4*)&w1B;
  f32x4 b1C;
#pragma unroll
  for (int r = 0; r < 4; ++r) b1C[r] = b1[(g * 4 + r) & 7];

  int w = tid >> 6;
  int wv = blockIdx.x * 8 + w;
  const int W = MLP_BLOCKS * 8;
  float keep = 0.f;

  for (int b = wv; b < NBATCH; b += W) {
    int t0 = b * TPB;

    bf16x8 xf0, xf1, xf2, xf3;
    if constexpr (MODE == 3) {
      // synthetic xf through the same cvt path; distinct per tile (no CSE)
      float fb = (float)(b & 2047) * 0.001f;
      uint4 ui;
#define SYNX(T, DST)                                               \
      ui.x = cvt_pk_bf16(fb + (float)T, 1.0f);                     \
      ui.y = cvt_pk_bf16(0.5f, fb - (float)T);                     \
      ui.z = cvt_pk_bf16(fb * 0.5f, 2.0f + (float)T);              \
      ui.w = cvt_pk_bf16(0.25f, fb + 0.125f * (float)T);           \
      DST = *(bf16x8*)&ui;
      SYNX(0, xf0) SYNX(1, xf1) SYNX(2, xf2) SYNX(3, xf3)
#undef SYNX
    } else {
      const float* xp;
      float4 a, c;
      uint4 ui;
#define LOADX(T, DST)                                              \
      xp = x + (long)((t0 + T) * 16 + n) * 32 + g * 8;             \
      a = *(const float4*)xp; c = *(const float4*)(xp + 4);        \
      ui.x = cvt_pk_bf16(a.x, a.y); ui.y = cvt_pk_bf16(a.z, a.w); \
      ui.z = cvt_pk_bf16(c.x, c.y); ui.w = cvt_pk_bf16(c.z, c.w); \
      DST = *(bf16x8*)&ui;
      LOADX(0, xf0) LOADX(1, xf1) LOADX(2, xf2) LOADX(3, xf3)
#undef LOADX
    }

    f32x4 O0 = b1C, O1 = b1C, O2 = b1C, O3 = b1C;

#pragma unroll 1
    for (int cp = 0; cp < 8; ++cp) {
      bool own = (n == cp);
      int4 z4 = {0, 0, 0, 0};
      int4 A2ai = own ? w1Ai : z4;
      int4 A2bi = own ? w1Bi : z4;
      bf16x8 A2a = *(bf16x8*)&A2ai;
      bf16x8 A2b = *(bf16x8*)&A2bi;
      int fb2 = cp * 4;
      bf16x8 Aw0 = *(const bf16x8*)&sA[(fb2 + 0) * 512 + l * 8];
      bf16x8 Aw1 = *(const bf16x8*)&sA[(fb2 + 1) * 512 + l * 8];
      bf16x8 Aw2 = *(const bf16x8*)&sA[(fb2 + 2) * 512 + l * 8];
      bf16x8 Aw3 = *(const bf16x8*)&sA[(fb2 + 3) * 512 + l * 8];
      f32x4 C0 = *(const f32x4*)&sB0[(fb2 + 0) * 16 + g * 4];
      f32x4 C1 = *(const f32x4*)&sB0[(fb2 + 1) * 16 + g * 4];
      f32x4 C2 = *(const f32x4*)&sB0[(fb2 + 2) * 16 + g * 4];
      f32x4 C3 = *(const f32x4*)&sB0[(fb2 + 3) * 16 + g * 4];

#define TILE(XF, OD) {                                                        \
      f32x4 Da = __builtin_amdgcn_mfma_f32_16x16x32_bf16(Aw0, XF, C0, 0,0,0); \
      f32x4 Db = __builtin_amdgcn_mfma_f32_16x16x32_bf16(Aw1, XF, C1, 0,0,0); \
      uint4 bu;                                                               \
      if constexpr (MODE == 2) {                                              \
        bu.x = __float_as_uint(Da[0]); bu.y = __float_as_uint(Da[2]);         \
        bu.z = __float_as_uint(Db[0]); bu.w = __float_as_uint(Db[2]);         \
      } else {                                                                \
        bu.x = cvt_pk_bf16(fmaxf(Da[0], 0.f), fmaxf(Da[1], 0.f));             \
        bu.y = cvt_pk_bf16(fmaxf(Da[2], 0.f), fmaxf(Da[3], 0.f));             \
        bu.z = cvt_pk_bf16(fmaxf(Db[0], 0.f), fmaxf(Db[1], 0.f));             \
        bu.w = cvt_pk_bf16(fmaxf(Db[2], 0.f), fmaxf(Db[3], 0.f));             \
      }                                                                       \
      bf16x8 B2 = *(bf16x8*)&bu;                                              \
      OD = __builtin_amdgcn_mfma_f32_16x16x32_bf16(A2a, B2, OD, 0, 0, 0);     \
      f32x4 Dc = __builtin_amdgcn_mfma_f32_16x16x32_bf16(Aw2, XF, C2, 0,0,0); \
      f32x4 Dd = __builtin_amdgcn_mfma_f32_16x16x32_bf16(Aw3, XF, C3, 0,0,0); \
      if constexpr (MODE == 2) {                                              \
        bu.x = __float_as_uint(Dc[0]); bu.y = __float_as_uint(Dc[2]);         \
        bu.z = __float_as_uint(Dd[0]); bu.w = __float_as_uint(Dd[2]);         \
      } else {                                                                \
        bu.x = cvt_pk_bf16(fmaxf(Dc[0], 0.f), fmaxf(Dc[1], 0.f));             \
        bu.y = cvt_pk_bf16(fmaxf(Dc[2], 0.f), fmaxf(Dc[3], 0.f));             \
        bu.z = cvt_pk_bf16(fmaxf(Dd[0], 0.f), fmaxf(Dd[1], 0.f));             \
        bu.w = cvt_pk_bf16(fmaxf(Dd[2], 0.f), fmaxf(Dd[3], 0.f));             \
      }                                                                       \
      bf16x8 B3 = *(bf16x8*)&bu;                                              \
      OD = __builtin_amdgcn_mfma_f32_16x16x32_bf16(A2b, B3, OD, 0, 0, 0); }
      TILE(xf0, O0) TILE(xf1, O1) TILE(xf2, O2) TILE(xf3, O3)
#undef TILE
    }

    if constexpr (MODE == 0) {
      if (g < 2) {
#define EPI(T, OD) {                                                     \
        int row = (t0 + T) * 16 + n;                                     \
        int info = rowinfo[row];                                         \
        unsigned mb = (unsigned)info & 255u;                             \
        int pos = (int)(((unsigned)info) >> 8) +                         \
                  (g ? __popc(mb & 0xFu) : 0);                           \
        unsigned nib = (mb >> (g * 4)) & 0xFu;                           \
        if (nib & 1u) { out[pos] = OD[0]; pos++; }                       \
        if (nib & 2u) { out[pos] = OD[1]; pos++; }                       \
        if (nib & 4u) { out[pos] = OD[2]; pos++; }                       \
        if (nib & 8u) { out[pos] = OD[3]; }                              }
        EPI(0, O0) EPI(1, O1) EPI(2, O2) EPI(3, O3)
#undef EPI
      }
    } else {
#pragma unroll
      for (int r = 0; r < 4; ++r)
        keep += O0[r] + O1[r] + O2[r] + O3[r];
    }
  }

  if constexpr (MODE != 0) dbg[blockIdx.x * MLP_THREADS + tid] = keep;
}

extern "C" void kernel_launch(void* const* d_in, const int* in_sizes, int n_in,
                              void* d_out, int out_size, void* d_ws, size_t ws_size,
                              hipStream_t stream) {
  const float* x    = (const float*)d_in[0];
  const int*   mask = (const int*)d_in[1];
  const float* w0   = (const float*)d_in[2];
  const float* b0   = (const float*)d_in[3];
  const float* w1   = (const float*)d_in[4];
  const float* b1   = (const float*)d_in[5];
  float* out = (float*)d_out;

  int* bsum    = (int*)d_ws;
  int* boff    = bsum + NB;
  int* rowinfo = boff + NB;
  float* dbg   = (float*)(rowinfo + NROWS);  // 768*512 floats ~ 1.6 MB

  count_kernel<<<NB, 256, 0, stream>>>(mask, bsum);
  scan_kernel<<<1, 1024, 0, stream>>>(bsum, boff);
  expand_kernel<<<NB, 256, 0, stream>>>(mask, boff, rowinfo);
  mlp_t<0><<<MLP_BLOCKS, MLP_THREADS, 0, stream>>>(x, w0, b0, w1, b1, rowinfo, out, dbg);
  mlp_t<1><<<MLP_BLOCKS, MLP_THREADS, 0, stream>>>(x, w0, b0, w1, b1, rowinfo, out, dbg);
  mlp_t<2><<<MLP_BLOCKS, MLP_THREADS, 0, stream>>>(x, w0, b0, w1, b1, rowinfo, out, dbg);
  mlp_t<3><<<MLP_BLOCKS, MLP_THREADS, 0, stream>>>(x, w0, b0, w1, b1, rowinfo, out, dbg);
}

// Round 14
// 95.593 us; speedup vs baseline: 2.5455x; 2.5455x over previous
//
#include <hip/hip_runtime.h>

#define NROWS 1000000
#define NB    3907         // ceil(1e6 / 256) mask blocks
#define NT    62500        // 16-row tiles
#define TPB   4            // tiles per wave-batch
#define NBATCH (NT / TPB)  // 15625, exact
#define MLP_BLOCKS 512     // 256-thr blocks; 2 resident/CU (VGPR-capped)
#define MLP_WAVES (MLP_BLOCKS * 4)   // 2048

typedef __bf16 bf16x8 __attribute__((ext_vector_type(8)));
typedef float  f32x4  __attribute__((ext_vector_type(4)));

__device__ __forceinline__ unsigned cvt_pk_bf16(float lo, float hi) {
  unsigned r;
  asm("v_cvt_pk_bf16_f32 %0, %1, %2" : "=v"(r) : "v"(lo), "v"(hi));
  return r;
}

// ---------------------------------------------------------------------------
// Kernel 1: per-256-row-block nonzero counts (3907 sums).
// ---------------------------------------------------------------------------
__global__ __launch_bounds__(256) void count_kernel(
    const int* __restrict__ mask, int* __restrict__ bsum) {
  int tid = threadIdx.x;
  int row = blockIdx.x * 256 + tid;
  int cnt = 0;
  if (row < NROWS) {
    const int4* mp = (const int4*)(mask + (long)row * 8);
    int4 a = mp[0], b = mp[1];
    cnt = (a.x != 0) + (a.y != 0) + (a.z != 0) + (a.w != 0) +
          (b.x != 0) + (b.y != 0) + (b.z != 0) + (b.w != 0);
  }
#pragma unroll
  for (int off = 1; off < 64; off <<= 1) cnt += __shfl_xor(cnt, off);
  __shared__ int ws[4];
  if ((tid & 63) == 0) ws[tid >> 6] = cnt;
  __syncthreads();
  if (tid == 0) bsum[blockIdx.x] = ws[0] + ws[1] + ws[2] + ws[3];
}

// ---------------------------------------------------------------------------
// Kernel 2: exclusive scan of 3907 block sums (single block).
// ---------------------------------------------------------------------------
__global__ __launch_bounds__(1024) void scan_kernel(
    const int* __restrict__ bsum, int* __restrict__ boff) {
  __shared__ int lds[1024];
  int t = threadIdx.x;
  int i0 = t * 4;
  int c0 = (i0 + 0 < NB) ? bsum[i0 + 0] : 0;
  int c1 = (i0 + 1 < NB) ? bsum[i0 + 1] : 0;
  int c2 = (i0 + 2 < NB) ? bsum[i0 + 2] : 0;
  int c3 = (i0 + 3 < NB) ? bsum[i0 + 3] : 0;
  int s = c0 + c1 + c2 + c3;
  lds[t] = s;
  __syncthreads();
  for (int off = 1; off < 1024; off <<= 1) {
    int v = lds[t];
    int add = (t >= off) ? lds[t - off] : 0;
    __syncthreads();
    lds[t] = v + add;
    __syncthreads();
  }
  int excl = lds[t] - s;
  if (i0 + 0 < NB) boff[i0 + 0] = excl;
  excl += c0;
  if (i0 + 1 < NB) boff[i0 + 1] = excl;
  excl += c1;
  if (i0 + 2 < NB) boff[i0 + 2] = excl;
  excl += c2;
  if (i0 + 3 < NB) boff[i0 + 3] = excl;
}

// ---------------------------------------------------------------------------
// Kernel 3: per-row info = (scatter_pos << 8) | mask_bits.
// ---------------------------------------------------------------------------
__global__ __launch_bounds__(256) void expand_kernel(
    const int* __restrict__ mask, const int* __restrict__ boff,
    int* __restrict__ rowinfo) {
  int tid = threadIdx.x;
  int row = blockIdx.x * 256 + tid;
  bool valid = row < NROWS;
  unsigned mb = 0;
  int cnt = 0;
  if (valid) {
    const int4* mp = (const int4*)(mask + (long)row * 8);
    int4 a = mp[0], b = mp[1];
    mb = (unsigned)((a.x != 0) | ((a.y != 0) << 1) | ((a.z != 0) << 2) |
                    ((a.w != 0) << 3) | ((b.x != 0) << 4) | ((b.y != 0) << 5) |
                    ((b.z != 0) << 6) | ((b.w != 0) << 7));
    cnt = __popc(mb);
  }
  int incl = cnt;
#pragma unroll
  for (int off = 1; off < 64; off <<= 1) {
    int v = __shfl_up(incl, off);
    if ((tid & 63) >= off) incl += v;
  }
  __shared__ int wsum[4];
  if ((tid & 63) == 63) wsum[tid >> 6] = incl;
  __syncthreads();
  int w = tid >> 6;
  int wo = 0;
  if (w > 0) wo += wsum[0];
  if (w > 1) wo += wsum[1];
  if (w > 2) wo += wsum[2];
  int pos = boff[blockIdx.x] + wo + (incl - cnt);
  if (valid) rowinfo[row] = (pos << 8) | (int)mb;
}

// ---------------------------------------------------------------------------
// Kernel 4: MFMA MLP, software-pipelined:
//  - head-pair loop w/ named double-buffered LDS fragment sets (A/B)
//  - cross-batch x prefetch (issue early, cvt at next batch top)
//  - split accumulators Oa/Ob (chain depth 16 -> 8), merged in epilogue
// ---------------------------------------------------------------------------
__global__ __launch_bounds__(256, 2) void mlp_kernel(
    const float* __restrict__ x, const float* __restrict__ w0,
    const float* __restrict__ b0, const float* __restrict__ w1,
    const float* __restrict__ b1, const int* __restrict__ rowinfo,
    float* __restrict__ out) {
  __shared__ __bf16 sA[32 * 64 * 8];
  __shared__ float sB0[512];

  int tid = threadIdx.x;
#pragma unroll
  for (int i = 0; i < 8; ++i) {
    int fi = i * 256 + tid;
    int frag = fi >> 6;
    int lane = fi & 63;
    int d = frag >> 2, qb = frag & 3;
    int q = qb * 16 + (lane & 15);
    int kb = (lane >> 4) * 8;
    bf16x8 v;
#pragma unroll
    for (int j = 0; j < 8; ++j)
      v[j] = (__bf16)w0[d * 2048 + (kb + j) * 64 + q];
    *(bf16x8*)&sA[fi * 8] = v;
  }
  if (tid < 128) *(float4*)&sB0[tid * 4] = *(const float4*)&b0[tid * 4];
  __syncthreads();

  int l = tid & 63;
  int n = l & 15;
  int g = l >> 4;

  bf16x8 w1A, w1B;
  bool ownrow = (n < 8);
#pragma unroll
  for (int j = 0; j < 8; ++j) {
    int off = (j >> 2) * 16 + g * 4 + (j & 3);
    w1A[j] = ownrow ? (__bf16)w1[n * 64 + off]      : (__bf16)0.f;
    w1B[j] = ownrow ? (__bf16)w1[n * 64 + 32 + off] : (__bf16)0.f;
  }
  int4 w1Ai = *(int4*)&w1A;
  int4 w1Bi = *(int4*)&w1B;
  f32x4 b1C;
#pragma unroll
  for (int r = 0; r < 4; ++r) b1C[r] = b1[(g * 4 + r) & 7];

  int w = tid >> 6;
  int wv = blockIdx.x * 4 + w;
  const int W = MLP_WAVES;

  // ---- issue first batch's x loads (8x dwordx4) ----
  float4 xa0, xa1, xa2, xa3, xa4, xa5, xa6, xa7;
  {
    const float* xp0 = x + (long)((wv * TPB + 0) * 16 + n) * 32 + g * 8;
    const float* xp1 = x + (long)((wv * TPB + 1) * 16 + n) * 32 + g * 8;
    const float* xp2 = x + (long)((wv * TPB + 2) * 16 + n) * 32 + g * 8;
    const float* xp3 = x + (long)((wv * TPB + 3) * 16 + n) * 32 + g * 8;
    xa0 = *(const float4*)xp0; xa1 = *(const float4*)(xp0 + 4);
    xa2 = *(const float4*)xp1; xa3 = *(const float4*)(xp1 + 4);
    xa4 = *(const float4*)xp2; xa5 = *(const float4*)(xp2 + 4);
    xa6 = *(const float4*)xp3; xa7 = *(const float4*)(xp3 + 4);
  }

  for (int b = wv; b < NBATCH; b += W) {
    int t0 = b * TPB;

    // ---- convert current x (loads issued one batch ago) ----
    bf16x8 xf0, xf1, xf2, xf3;
    {
      uint4 ui;
#define CVTX(P, Q, DST)                                            \
      ui.x = cvt_pk_bf16(P.x, P.y); ui.y = cvt_pk_bf16(P.z, P.w);  \
      ui.z = cvt_pk_bf16(Q.x, Q.y); ui.w = cvt_pk_bf16(Q.z, Q.w);  \
      DST = *(bf16x8*)&ui;
      CVTX(xa0, xa1, xf0) CVTX(xa2, xa3, xf1)
      CVTX(xa4, xa5, xf2) CVTX(xa6, xa7, xf3)
#undef CVTX
    }

    // ---- issue next batch's x loads (hidden under head loop) ----
    {
      int bn = b + W;
      if (bn >= NBATCH) bn = b;  // clamp; results unused after last batch
      const float* yp0 = x + (long)((bn * TPB + 0) * 16 + n) * 32 + g * 8;
      const float* yp1 = x + (long)((bn * TPB + 1) * 16 + n) * 32 + g * 8;
      const float* yp2 = x + (long)((bn * TPB + 2) * 16 + n) * 32 + g * 8;
      const float* yp3 = x + (long)((bn * TPB + 3) * 16 + n) * 32 + g * 8;
      xa0 = *(const float4*)yp0; xa1 = *(const float4*)(yp0 + 4);
      xa2 = *(const float4*)yp1; xa3 = *(const float4*)(yp1 + 4);
      xa4 = *(const float4*)yp2; xa5 = *(const float4*)(yp2 + 4);
      xa6 = *(const float4*)yp3; xa7 = *(const float4*)(yp3 + 4);
    }

    f32x4 Oa0 = b1C, Oa1 = b1C, Oa2 = b1C, Oa3 = b1C;
    f32x4 Ob0 = {0.f, 0.f, 0.f, 0.f}, Ob1 = Ob0, Ob2 = Ob0, Ob3 = Ob0;

    // ---- preload head 0 fragment set (A) ----
    bf16x8 fA0 = *(const bf16x8*)&sA[0 * 512 + l * 8];
    bf16x8 fA1 = *(const bf16x8*)&sA[1 * 512 + l * 8];
    bf16x8 fA2 = *(const bf16x8*)&sA[2 * 512 + l * 8];
    bf16x8 fA3 = *(const bf16x8*)&sA[3 * 512 + l * 8];
    f32x4 cA0 = *(const f32x4*)&sB0[0 * 16 + g * 4];
    f32x4 cA1 = *(const f32x4*)&sB0[1 * 16 + g * 4];
    f32x4 cA2 = *(const f32x4*)&sB0[2 * 16 + g * 4];
    f32x4 cA3 = *(const f32x4*)&sB0[3 * 16 + g * 4];

#define COMPUTE(CP, F0, F1, F2, F3, C0v, C1v, C2v, C3v)                       \
    {                                                                         \
      bool own = (n == (CP));                                                 \
      int4 z4 = {0, 0, 0, 0};                                                 \
      int4 A2ai = own ? w1Ai : z4;                                            \
      int4 A2bi = own ? w1Bi : z4;                                            \
      bf16x8 A2a = *(bf16x8*)&A2ai;                                           \
      bf16x8 A2b = *(bf16x8*)&A2bi;                                           \
      TILE(xf0, F0, F1, F2, F3, C0v, C1v, C2v, C3v, Oa0, Ob0)                 \
      TILE(xf1, F0, F1, F2, F3, C0v, C1v, C2v, C3v, Oa1, Ob1)                 \
      TILE(xf2, F0, F1, F2, F3, C0v, C1v, C2v, C3v, Oa2, Ob2)                 \
      TILE(xf3, F0, F1, F2, F3, C0v, C1v, C2v, C3v, Oa3, Ob3)                 \
    }
#define TILE(XF, F0, F1, F2, F3, C0v, C1v, C2v, C3v, OA, OB) {                \
      f32x4 Da = __builtin_amdgcn_mfma_f32_16x16x32_bf16(F0, XF, C0v, 0,0,0); \
      f32x4 Db = __builtin_amdgcn_mfma_f32_16x16x32_bf16(F1, XF, C1v, 0,0,0); \
      uint4 bu;                                                               \
      bu.x = cvt_pk_bf16(fmaxf(Da[0], 0.f), fmaxf(Da[1], 0.f));               \
      bu.y = cvt_pk_bf16(fmaxf(Da[2], 0.f), fmaxf(Da[3], 0.f));               \
      bu.z = cvt_pk_bf16(fmaxf(Db[0], 0.f), fmaxf(Db[1], 0.f));               \
      bu.w = cvt_pk_bf16(fmaxf(Db[2], 0.f), fmaxf(Db[3], 0.f));               \
      bf16x8 B2 = *(bf16x8*)&bu;                                              \
      OA = __builtin_amdgcn_mfma_f32_16x16x32_bf16(A2a, B2, OA, 0, 0, 0);     \
      f32x4 Dc = __builtin_amdgcn_mfma_f32_16x16x32_bf16(F2, XF, C2v, 0,0,0); \
      f32x4 Dd = __builtin_amdgcn_mfma_f32_16x16x32_bf16(F3, XF, C3v, 0,0,0); \
      bu.x = cvt_pk_bf16(fmaxf(Dc[0], 0.f), fmaxf(Dc[1], 0.f));               \
      bu.y = cvt_pk_bf16(fmaxf(Dc[2], 0.f), fmaxf(Dc[3], 0.f));               \
      bu.z = cvt_pk_bf16(fmaxf(Dd[0], 0.f), fmaxf(Dd[1], 0.f));               \
      bu.w = cvt_pk_bf16(fmaxf(Dd[2], 0.f), fmaxf(Dd[3], 0.f));               \
      bf16x8 B3 = *(bf16x8*)&bu;                                              \
      OB = __builtin_amdgcn_mfma_f32_16x16x32_bf16(A2b, B3, OB, 0, 0, 0); }

#pragma unroll 1
    for (int pp = 0; pp < 4; ++pp) {
      int cpA = pp * 2, cpB = pp * 2 + 1;
      int cpN = (pp * 2 + 2) & 7;  // wraps at pp=3 (reload head 0; unused)
      int fbB = cpB * 4, fbN = cpN * 4;
      // load set B (head cpB) -- overlaps with COMPUTE(cpA)
      bf16x8 fB0 = *(const bf16x8*)&sA[(fbB + 0) * 512 + l * 8];
      bf16x8 fB1 = *(const bf16x8*)&sA[(fbB + 1) * 512 + l * 8];
      bf16x8 fB2 = *(const bf16x8*)&sA[(fbB + 2) * 512 + l * 8];
      bf16x8 fB3 = *(const bf16x8*)&sA[(fbB + 3) * 512 + l * 8];
      f32x4 cB0 = *(const f32x4*)&sB0[(fbB + 0) * 16 + g * 4];
      f32x4 cB1 = *(const f32x4*)&sB0[(fbB + 1) * 16 + g * 4];
      f32x4 cB2 = *(const f32x4*)&sB0[(fbB + 2) * 16 + g * 4];
      f32x4 cB3 = *(const f32x4*)&sB0[(fbB + 3) * 16 + g * 4];
      COMPUTE(cpA, fA0, fA1, fA2, fA3, cA0, cA1, cA2, cA3)
      // load set A (head cpN) -- overlaps with COMPUTE(cpB)
      fA0 = *(const bf16x8*)&sA[(fbN + 0) * 512 + l * 8];
      fA1 = *(const bf16x8*)&sA[(fbN + 1) * 512 + l * 8];
      fA2 = *(const bf16x8*)&sA[(fbN + 2) * 512 + l * 8];
      fA3 = *(const bf16x8*)&sA[(fbN + 3) * 512 + l * 8];
      cA0 = *(const f32x4*)&sB0[(fbN + 0) * 16 + g * 4];
      cA1 = *(const f32x4*)&sB0[(fbN + 1) * 16 + g * 4];
      cA2 = *(const f32x4*)&sB0[(fbN + 2) * 16 + g * 4];
      cA3 = *(const f32x4*)&sB0[(fbN + 3) * 16 + g * 4];
      COMPUTE(cpB, fB0, fB1, fB2, fB3, cB0, cB1, cB2, cB3)
    }
#undef TILE
#undef COMPUTE

    // ---- epilogue: merge accumulators, ordered scatter ----
    if (g < 2) {
      f32x4 Os0 = Oa0 + Ob0, Os1 = Oa1 + Ob1;
      f32x4 Os2 = Oa2 + Ob2, Os3 = Oa3 + Ob3;
#define EPI(T, OD) {                                                     \
      int row = (t0 + T) * 16 + n;                                       \
      int info = rowinfo[row];                                           \
      unsigned mb = (unsigned)info & 255u;                               \
      int pos = (int)(((unsigned)info) >> 8) +                           \
                (g ? __popc(mb & 0xFu) : 0);                             \
      unsigned nib = (mb >> (g * 4)) & 0xFu;                             \
      if (nib & 1u) { out[pos] = OD[0]; pos++; }                         \
      if (nib & 2u) { out[pos] = OD[1]; pos++; }                         \
      if (nib & 4u) { out[pos] = OD[2]; pos++; }                         \
      if (nib & 8u) { out[pos] = OD[3]; }                                }
      EPI(0, Os0) EPI(1, Os1) EPI(2, Os2) EPI(3, Os3)
#undef EPI
    }
  }
}

extern "C" void kernel_launch(void* const* d_in, const int* in_sizes, int n_in,
                              void* d_out, int out_size, void* d_ws, size_t ws_size,
                              hipStream_t stream) {
  const float* x    = (const float*)d_in[0];
  const int*   mask = (const int*)d_in[1];
  const float* w0   = (const float*)d_in[2];
  const float* b0   = (const float*)d_in[3];
  const float* w1   = (const float*)d_in[4];
  const float* b1   = (const float*)d_in[5];
  float* out = (float*)d_out;

  int* bsum    = (int*)d_ws;
  int* boff    = bsum + NB;
  int* rowinfo = boff + NB;

  count_kernel<<<NB, 256, 0, stream>>>(mask, bsum);
  scan_kernel<<<1, 1024, 0, stream>>>(bsum, boff);
  expand_kernel<<<NB, 256, 0, stream>>>(mask, boff, rowinfo);
  mlp_kernel<<<MLP_BLOCKS, 256, 0, stream>>>(x, w0, b0, w1, b1, rowinfo, out);
}